// Round 7
// baseline (510.413 us; speedup 1.0000x reference)
//
#include <hip/hip_runtime.h>
#include <hip/hip_bf16.h>

// GCN: h1 = relu(Agg(x@W1)+b1); h2 = relu(Agg(h1@W2)+b2); out = mean(h2)@Wc + bc
// Agg via CSR gather; g = (X@W)*dinv stored as OCP fp8 e4m3 (128B rows) to halve
// the structural agg fetch floor (8 XCDs x g-buffer). CSR build XCD-partitioned
// with non-temporal streaming reads so dirty csr_src lines survive in L2.
// GEMMs: mfma_f32_16x16x32_bf16, LDS-free, W pre-packed to k-block layout.

#define FEAT 128
#define CHUNK 16384   // edges per chunk (multiple of 4 for int4 alignment)

typedef __attribute__((ext_vector_type(8))) short short8;
typedef __attribute__((ext_vector_type(4))) float float4v;
typedef __attribute__((ext_vector_type(2))) float floatx2;
typedef __attribute__((ext_vector_type(4))) int int4v;

union I4S8 { int4 i; short8 s; };

static __device__ inline unsigned short f2bf(float f) {
    union { __hip_bfloat16 h; unsigned short u; } cv;
    cv.h = __float2bfloat16(f);
    return cv.u;
}

// ---- OCP fp8 e4m3 helpers ----
static __device__ inline floatx2 fp8x2_dec(unsigned int u) {
#if __has_builtin(__builtin_amdgcn_cvt_pk_f32_fp8)
    return __builtin_amdgcn_cvt_pk_f32_fp8((int)u, false);
#else
    floatx2 r;
    unsigned int b0 = u & 0xFFu, b1 = (u >> 8) & 0xFFu;
    r.x = __uint_as_float(((b0 & 0x80u) << 24) | ((b0 & 0x7Fu) << 20)) * 0x1p+120f;
    r.y = __uint_as_float(((b1 & 0x80u) << 24) | ((b1 & 0x7Fu) << 20)) * 0x1p+120f;
    return r;
#endif
}

static __device__ inline unsigned char fp8enc(float f) {
#if __has_builtin(__builtin_amdgcn_cvt_pk_fp8_f32)
    return (unsigned char)(__builtin_amdgcn_cvt_pk_fp8_f32(f, 0.0f, 0, false) & 0xFF);
#else
    unsigned int u = __float_as_uint(f);
    unsigned int s = (u >> 24) & 0x80u;
    float a = fabsf(f);
    a = fminf(a, 448.0f);
    unsigned int code;
    if (a < 0.015625f) {                       // denormal range, steps of 2^-9
        code = (unsigned int)(int)rintf(a * 512.0f);   // 0..8 (8 -> 2^-6 normal)
    } else {
        unsigned int au = __float_as_uint(a);
        unsigned int r = au + 0x0007FFFFu + ((au >> 20) & 1u);  // RNE at bit 20
        unsigned int e = (r >> 23) - 120u;
        unsigned int m = (r >> 20) & 7u;
        code = (e << 3) | m;
        if (code > 0x7Eu) code = 0x7Eu;        // clamp to 448 (0x7F = NaN)
    }
    return (unsigned char)(code | s);
#endif
}

// ---- degree count, XCD-partitioned, NT streaming reads ----
__global__ __launch_bounds__(256) void count_xcd(const int* __restrict__ dst,
                                                 int* __restrict__ cnt, int nE,
                                                 float pscale) {
    int part  = blockIdx.x & 7;
    int chunk = blockIdx.x >> 3;
    int beg = chunk * CHUNK;
    int end = min(nE, beg + CHUNK);
    for (int e = beg + (int)threadIdx.x * 4; e < end; e += 1024) {
        if (e + 3 < end) {
            int4v d4 = __builtin_nontemporal_load((const int4v*)(dst + e));
            if ((int)(d4.x * pscale) == part) atomicAdd(&cnt[d4.x], 1);
            if ((int)(d4.y * pscale) == part) atomicAdd(&cnt[d4.y], 1);
            if ((int)(d4.z * pscale) == part) atomicAdd(&cnt[d4.z], 1);
            if ((int)(d4.w * pscale) == part) atomicAdd(&cnt[d4.w], 1);
        } else {
            for (int k = e; k < end; k++) {
                int d = dst[k];
                if ((int)(d * pscale) == part) atomicAdd(&cnt[d], 1);
            }
        }
    }
}

// ---- scan K1: per-block (1024 elems) sums ----
__global__ __launch_bounds__(256) void scan_bsum(const int* __restrict__ cnt,
                                                 int* __restrict__ bsum, int n) {
    __shared__ int red[256];
    int b = blockIdx.x, t = threadIdx.x;
    int base = b * 1024 + t * 4;
    int s = 0;
#pragma unroll
    for (int k = 0; k < 4; k++) {
        int i = base + k;
        if (i < n) s += cnt[i];
    }
    red[t] = s;
    __syncthreads();
    for (int off = 128; off > 0; off >>= 1) {
        if (t < off) red[t] += red[t + off];
        __syncthreads();
    }
    if (t == 0) bsum[b] = red[0];
}

// ---- scan K2: exclusive scan of block sums (single thread; nb ~ 98) ----
__global__ void scan_boff(const int* __restrict__ bsum, int* __restrict__ boff, int nb) {
    int run = 0;
    for (int i = 0; i < nb; i++) { boff[i] = run; run += bsum[i]; }
}

// ---- scan K3: cursor[i] = global exclusive prefix; also dinv = rsqrt(cnt+1) ----
__global__ __launch_bounds__(256) void scan_write(const int* __restrict__ cnt,
                                                  const int* __restrict__ boff,
                                                  int* __restrict__ cursor,
                                                  float* __restrict__ dinv, int n) {
    __shared__ int sc[256];
    int b = blockIdx.x, t = threadIdx.x;
    int base = b * 1024 + t * 4;
    int v[4];
    int s = 0;
#pragma unroll
    for (int k = 0; k < 4; k++) {
        int i = base + k;
        v[k] = (i < n) ? cnt[i] : 0;
        s += v[k];
    }
    sc[t] = s;
    __syncthreads();
    for (int off = 1; off < 256; off <<= 1) {
        int add = (t >= off) ? sc[t - off] : 0;
        __syncthreads();
        sc[t] += add;
        __syncthreads();
    }
    int excl = boff[b] + sc[t] - s;
#pragma unroll
    for (int k = 0; k < 4; k++) {
        int i = base + k;
        if (i < n) {
            cursor[i] = excl;
            dinv[i] = rsqrtf((float)(v[k] + 1));
        }
        excl += v[k];
    }
}

// ---- scatter edges into CSR buckets, XCD-partitioned, NT streaming reads ----
__global__ __launch_bounds__(256) void csr_scatter_xcd(const int* __restrict__ src,
                                                       const int* __restrict__ dst,
                                                       int* __restrict__ cursor,
                                                       int* __restrict__ csr_src,
                                                       int nE, float pscale) {
    int part  = blockIdx.x & 7;
    int chunk = blockIdx.x >> 3;
    int beg = chunk * CHUNK;
    int end = min(nE, beg + CHUNK);
    for (int e = beg + (int)threadIdx.x * 4; e < end; e += 1024) {
        if (e + 3 < end) {
            int4v d4 = __builtin_nontemporal_load((const int4v*)(dst + e));
            if ((int)(d4.x * pscale) == part) {
                int pos = atomicAdd(&cursor[d4.x], 1);
                csr_src[pos] = __builtin_nontemporal_load(src + e + 0);
            }
            if ((int)(d4.y * pscale) == part) {
                int pos = atomicAdd(&cursor[d4.y], 1);
                csr_src[pos] = __builtin_nontemporal_load(src + e + 1);
            }
            if ((int)(d4.z * pscale) == part) {
                int pos = atomicAdd(&cursor[d4.z], 1);
                csr_src[pos] = __builtin_nontemporal_load(src + e + 2);
            }
            if ((int)(d4.w * pscale) == part) {
                int pos = atomicAdd(&cursor[d4.w], 1);
                csr_src[pos] = __builtin_nontemporal_load(src + e + 3);
            }
        } else {
            for (int k = e; k < end; k++) {
                int d = dst[k];
                if ((int)(d * pscale) == part) {
                    int pos = atomicAdd(&cursor[d], 1);
                    csr_src[pos] = src[k];
                }
            }
        }
    }
}

// ---- W pre-pack: Wbf[(kb*128+n)*8+j] = bf16(W[(kb*8+j)*128+n]) ----
__global__ __launch_bounds__(256) void wprep(const float* __restrict__ W,
                                             unsigned short* __restrict__ Wbf) {
    int tid = blockIdx.x * 256 + threadIdx.x;   // 16384 threads
    int chunk = tid >> 3, j = tid & 7;
    int kb = chunk >> 7, nn = chunk & 127;
    Wbf[tid] = f2bf(W[(kb * 8 + j) * FEAT + nn]);
}

// ---- MFMA GEMM: gout[N][128](fp8) = bf16(X) @ Wbf * dinv[row] ----
// Block = 4 waves, wave = 16 rows x 128 cols. AFP32: A is fp32 (layer 1).
template <bool AFP32>
__global__ __launch_bounds__(256) void gemm_mfma(const void* __restrict__ Xv,
                                                 const unsigned short* __restrict__ Wbf,
                                                 const float* __restrict__ dinv,
                                                 unsigned char* __restrict__ gout,
                                                 int n) {
    int wave = threadIdx.x >> 6, lane = threadIdx.x & 63;
    int m0 = blockIdx.x * 64 + wave * 16;
    if (m0 >= n) return;
    int col = lane & 15, quad = lane >> 4;
    int mc = min(m0 + col, n - 1);

    // A fragments: afr[ks] = A[m][ks*32 + quad*8 .. +7]
    short8 afr[4];
    if (AFP32) {
        const float* X = (const float*)Xv;
        const float* xr = X + (size_t)mc * FEAT + quad * 8;
#pragma unroll
        for (int ks = 0; ks < 4; ks++) {
            float4 lo = *(const float4*)(xr + ks * 32);
            float4 hi = *(const float4*)(xr + ks * 32 + 4);
            short8 a;
            a[0] = (short)f2bf(lo.x); a[1] = (short)f2bf(lo.y);
            a[2] = (short)f2bf(lo.z); a[3] = (short)f2bf(lo.w);
            a[4] = (short)f2bf(hi.x); a[5] = (short)f2bf(hi.y);
            a[6] = (short)f2bf(hi.z); a[7] = (short)f2bf(hi.w);
            afr[ks] = a;
        }
    } else {
        const int4* X = (const int4*)Xv;           // 8 bf16 per int4
        const int4* xr = X + (size_t)mc * (FEAT / 8) + quad;
#pragma unroll
        for (int ks = 0; ks < 4; ks++) {
            I4S8 u; u.i = xr[ks * 4];
            afr[ks] = u.s;
        }
    }

    float dvr[4];
#pragma unroll
    for (int r = 0; r < 4; r++)
        dvr[r] = dinv[min(m0 + quad * 4 + r, n - 1)];

    const int4* Wb = (const int4*)Wbf;             // one int4 = one 8-elem chunk
#pragma unroll
    for (int nt = 0; nt < 8; nt++) {
        float4v acc = {0.f, 0.f, 0.f, 0.f};
#pragma unroll
        for (int ks = 0; ks < 4; ks++) {
            int kb = ks * 4 + quad;
            I4S8 u; u.i = Wb[kb * FEAT + nt * 16 + col];
            acc = __builtin_amdgcn_mfma_f32_16x16x32_bf16(afr[ks], u.s, acc, 0, 0, 0);
        }
#pragma unroll
        for (int r = 0; r < 4; r++) {
            int row = m0 + quad * 4 + r;
            if (row < n)
                gout[(size_t)row * FEAT + nt * 16 + col] = fp8enc(acc[r] * dvr[r]);
        }
    }
}

// ---- fused CSR aggregate + bias + relu. One wave/node, 2 fp8 feats/lane ----
__global__ __launch_bounds__(256) void agg_csr(const int* __restrict__ cursor,
                                               const int* __restrict__ cnt,
                                               const int* __restrict__ csr_src,
                                               const unsigned short* __restrict__ gs,
                                               const float* __restrict__ dinv,
                                               const float* __restrict__ bias,
                                               __hip_bfloat162* __restrict__ outb,
                                               int n) {
    int node = blockIdx.x * 4 + (threadIdx.x >> 6);
    if (node >= n) return;
    int lane = threadIdx.x & 63;

    int num = cnt[node];
    int end = cursor[node];       // after scatter, cursor = bucket end
    int beg = end - num;

    floatx2 sl = fp8x2_dec(gs[(size_t)node * 64 + lane]);   // self-loop term
    float ax[4] = {sl.x, 0.f, 0.f, 0.f};
    float ay[4] = {sl.y, 0.f, 0.f, 0.f};

    int j = beg;
    for (; j + 15 < end; j += 16) {
        int sIdx[16];
#pragma unroll
        for (int k = 0; k < 16; k++) sIdx[k] = csr_src[j + k];
        unsigned int uu[16];
#pragma unroll
        for (int k = 0; k < 16; k++) uu[k] = gs[(size_t)sIdx[k] * 64 + lane];
#pragma unroll
        for (int k = 0; k < 16; k++) {
            floatx2 v = fp8x2_dec(uu[k]);
            ax[k & 3] += v.x;
            ay[k & 3] += v.y;
        }
    }
    for (; j + 3 < end; j += 4) {
        int sIdx[4];
#pragma unroll
        for (int k = 0; k < 4; k++) sIdx[k] = csr_src[j + k];
        unsigned int uu[4];
#pragma unroll
        for (int k = 0; k < 4; k++) uu[k] = gs[(size_t)sIdx[k] * 64 + lane];
#pragma unroll
        for (int k = 0; k < 4; k++) {
            floatx2 v = fp8x2_dec(uu[k]);
            ax[k] += v.x;
            ay[k] += v.y;
        }
    }
    for (; j < end; j++) {
        floatx2 v = fp8x2_dec(gs[(size_t)csr_src[j] * 64 + lane]);
        ax[0] += v.x;
        ay[0] += v.y;
    }

    float dv = dinv[node];
    float2 bv = ((const float2*)bias)[lane];
    float sx = (ax[0] + ax[1]) + (ax[2] + ax[3]);
    float sy = (ay[0] + ay[1]) + (ay[2] + ay[3]);
    float2 r;
    r.x = fmaxf(sx * dv + bv.x, 0.0f);
    r.y = fmaxf(sy * dv + bv.y, 0.0f);
    outb[(size_t)node * 64 + lane] = __float22bfloat162_rn(r);
}

// ---- mean pool stage 1 (bf16 input) ----
__global__ __launch_bounds__(256) void pool_kernel(const __hip_bfloat16* __restrict__ a,
                                                   float* __restrict__ pooled, int n) {
    int tid = blockIdx.x * 256 + threadIdx.x;  // 256 blocks -> 65536 threads
    int f = tid & 127;
    int i0 = tid >> 7;  // 0..511
    float s = 0.0f;
    for (int i = i0; i < n; i += 512) s += __bfloat162float(a[(size_t)i * FEAT + f]);
    atomicAdd(&pooled[f], s);
}

// ---- final: out[c] = (pooled/N) . Wc[:,c] + bc[c] ----
__global__ __launch_bounds__(128) void final_kernel(const float* __restrict__ pooled,
                                                    const float* __restrict__ Wc,
                                                    const float* __restrict__ bc,
                                                    float* __restrict__ out,
                                                    int n, int C) {
    __shared__ float p[FEAT];
    int t = threadIdx.x;
    p[t] = pooled[t] * (1.0f / (float)n);
    __syncthreads();
    if (t < C) {
        float acc = bc[t];
        for (int h = 0; h < FEAT; h++)
            acc += p[h] * Wc[h * C + t];
        out[t] = acc;
    }
}

extern "C" void kernel_launch(void* const* d_in, const int* in_sizes, int n_in,
                              void* d_out, int out_size, void* d_ws, size_t ws_size,
                              hipStream_t stream) {
    const float* x  = (const float*)d_in[0];
    const int*   ei = (const int*)d_in[1];
    const float* W1 = (const float*)d_in[2];
    const float* b1 = (const float*)d_in[3];
    const float* W2 = (const float*)d_in[4];
    const float* b2 = (const float*)d_in[5];
    const float* Wc = (const float*)d_in[6];
    const float* bc = (const float*)d_in[7];

    const int N = in_sizes[0] / FEAT;      // 100000
    const int E = in_sizes[1] / 2;         // 1600000
    const int C = out_size;                // 32
    const int* srcI = ei;
    const int* dstI = ei + E;
    const int NB = (N + 1023) / 1024;      // scan blocks
    const int NC = (E + CHUNK - 1) / CHUNK;
    const float pscale = 8.0f / (float)N;  // dst -> partition in [0,8)

    // workspace carve (256B aligned)
    auto align256 = [](size_t v) { return (v + 255) & ~(size_t)255; };
    char* w = (char*)d_ws;
    int*            cnt     = (int*)w;            w += align256((size_t)N * 4);
    float*          dinv    = (float*)w;          w += align256((size_t)N * 4);
    int*            cursor  = (int*)w;            w += align256((size_t)N * 4);
    int*            csr_src = (int*)w;            w += align256((size_t)E * 4);
    int*            bsum    = (int*)w;            w += align256((size_t)NB * 4);
    int*            boff    = (int*)w;            w += align256((size_t)NB * 4);
    unsigned short* Wbf1    = (unsigned short*)w; w += align256((size_t)FEAT * FEAT * 2);
    unsigned short* Wbf2    = (unsigned short*)w; w += align256((size_t)FEAT * FEAT * 2);
    unsigned char*  gbuf    = (unsigned char*)w;  w += align256((size_t)N * FEAT);
    unsigned short* bufA    = (unsigned short*)w; w += align256((size_t)N * FEAT * 2);
    float*          pooled  = (float*)w;          w += align256((size_t)FEAT * 4);

    hipMemsetAsync(cnt, 0, (size_t)N * 4, stream);
    hipMemsetAsync(pooled, 0, (size_t)FEAT * 4, stream);

    // W pre-pack (tiny)
    wprep<<<64, 256, 0, stream>>>(W1, Wbf1);
    wprep<<<64, 256, 0, stream>>>(W2, Wbf2);

    // degrees (XCD-partitioned count)
    count_xcd<<<NC * 8, 256, 0, stream>>>(dstI, cnt, E, pscale);

    // CSR build (shared by both layers); dinv fused into scan_write
    scan_bsum<<<NB, 256, 0, stream>>>(cnt, bsum, N);
    scan_boff<<<1, 1, 0, stream>>>(bsum, boff, NB);
    scan_write<<<NB, 256, 0, stream>>>(cnt, boff, cursor, dinv, N);
    csr_scatter_xcd<<<NC * 8, 256, 0, stream>>>(srcI, dstI, cursor, csr_src, E, pscale);

    const int gAgg = (N + 3) / 4;
    const int gGemm = (N + 63) / 64;

    // ---- layer 1 ----
    gemm_mfma<true><<<gGemm, 256, 0, stream>>>(x, Wbf1, dinv, gbuf, N);
    agg_csr<<<gAgg, 256, 0, stream>>>(cursor, cnt, csr_src,
                                      (const unsigned short*)gbuf, dinv, b1,
                                      (__hip_bfloat162*)bufA, N);

    // ---- layer 2 ----
    gemm_mfma<false><<<gGemm, 256, 0, stream>>>(bufA, Wbf2, dinv, gbuf, N);
    agg_csr<<<gAgg, 256, 0, stream>>>(cursor, cnt, csr_src,
                                      (const unsigned short*)gbuf, dinv, b2,
                                      (__hip_bfloat162*)bufA, N);

    // ---- pool + classifier ----
    pool_kernel<<<256, 256, 0, stream>>>((const __hip_bfloat16*)bufA, pooled, N);
    final_kernel<<<1, 128, 0, stream>>>(pooled, Wc, bc, (float*)d_out, N, C);
}